// Round 5
// baseline (397.229 us; speedup 1.0000x reference)
//
#include <hip/hip_runtime.h>
#include <hip/hip_bf16.h>

#define EPSB 1e-5f

typedef __hip_bfloat16 bf16;
typedef __attribute__((ext_vector_type(8))) short bf16x8;
typedef __attribute__((ext_vector_type(4))) float f32x4;

__device__ __forceinline__ unsigned short f2bu(float x) {
  bf16 h = __float2bfloat16(x);
  return *reinterpret_cast<unsigned short*>(&h);
}
__device__ __forceinline__ unsigned int pk2(float lo, float hi) {
  return ((unsigned int)f2bu(hi) << 16) | (unsigned int)f2bu(lo);
}

// ---------------------------------------------------------------- sub = x1-x2
__global__ __launch_bounds__(256) void k_sub(const float* __restrict__ x1,
                                             const float* __restrict__ x2,
                                             float* __restrict__ sub) {
  int i = blockIdx.x * 256 + threadIdx.x;
  sub[i] = x1[i] - x2[i];
}

// ------------------------------------------- grouped 3x3 conv (2 in ch/group)
__global__ __launch_bounds__(256) void k_dwconv(const float* __restrict__ sub,
                                                const float* __restrict__ xs,
                                                const float* __restrict__ w,
                                                const float* __restrict__ bias,
                                                float* __restrict__ h) {
  int idx = blockIdx.x * 256 + threadIdx.x;   // 4*512*4096
  int pix = idx & 4095;
  int o   = (idx >> 12) & 511;
  int b   = idx >> 21;
  int y = pix >> 6, x = pix & 63;
  float wr[18];
  const float* wp = w + o * 18;
#pragma unroll
  for (int i = 0; i < 18; i++) wr[i] = wp[i];
  float acc = bias[o];
  int cbase = (o & ~1) & 255;
  bool use_sub = (o < 256);
  const float* s0 = (use_sub ? sub : xs) + ((size_t)(b * 256 + cbase) << 12);
#pragma unroll
  for (int ky = 0; ky < 3; ky++) {
    int yy = y + ky - 1;
    if (yy < 0 || yy > 63) continue;
#pragma unroll
    for (int kx = 0; kx < 3; kx++) {
      int xx = x + kx - 1;
      if (xx < 0 || xx > 63) continue;
      int off = yy * 64 + xx;
      acc += wr[ky * 3 + kx] * s0[off] + wr[9 + ky * 3 + kx] * s0[4096 + off];
    }
  }
  h[idx] = acc;
}

// --------------------- MFMA 1x1-conv GEMM (OC=256): Out[oc,p] = W[oc,:]@In[:,p]
__global__ __launch_bounds__(256) void k_gemm_mfma(
    const float* __restrict__ In, const float* __restrict__ W,
    const float* __restrict__ bias,
    const float* __restrict__ bng, const float* __restrict__ bnb,
    const float* __restrict__ bnm, const float* __restrict__ bnv,
    int has_bn, int relu, int out_bf16,
    void* __restrict__ OutV, int IC) {
  __shared__ __align__(16) bf16 Al[128][40];   // [oc][k]
  __shared__ __align__(16) bf16 Bl[64][40];    // [p][k]

  int t = threadIdx.x;
  int w = t >> 6, lane = t & 63, l16 = lane & 15, quad = lane >> 4;
  int wr = w >> 1, wc = w & 1;
  int p0 = blockIdx.x * 64;
  int oc0 = blockIdx.y * 128;
  int b = blockIdx.z;
  const float* Inb = In + (size_t)b * IC * 4096;

  f32x4 acc[4][2];
#pragma unroll
  for (int mi = 0; mi < 4; mi++)
#pragma unroll
    for (int nj = 0; nj < 2; nj++) acc[mi][nj] = (f32x4){0.f, 0.f, 0.f, 0.f};

  int sl = t & 15, srp = t >> 4;
  int ocl = t >> 1, kb = (t & 1) * 16;

  for (int kc = 0; kc < IC; kc += 32) {
    __syncthreads();
    {   // stage A: 128oc x 32k
      const float* src = W + (size_t)(oc0 + ocl) * IC + kc + kb;
      float4 f0 = *(const float4*)(src);
      float4 f1 = *(const float4*)(src + 4);
      float4 f2 = *(const float4*)(src + 8);
      float4 f3 = *(const float4*)(src + 12);
      uint4 u0 = {pk2(f0.x, f0.y), pk2(f0.z, f0.w), pk2(f1.x, f1.y), pk2(f1.z, f1.w)};
      uint4 u1 = {pk2(f2.x, f2.y), pk2(f2.z, f2.w), pk2(f3.x, f3.y), pk2(f3.z, f3.w)};
      *(uint4*)&Al[ocl][kb] = u0;
      *(uint4*)&Al[ocl][kb + 8] = u1;
    }
    {   // stage B: 32k x 64p transpose
      const float* re = Inb + (size_t)(kc + 2 * srp) * 4096 + p0 + sl;
      const float* ro = re + 4096;
#pragma unroll
      for (int j = 0; j < 4; j++) {
        float e = re[j * 16];
        float o = ro[j * 16];
        *(unsigned int*)&Bl[j * 16 + sl][2 * srp] = pk2(e, o);
      }
    }
    __syncthreads();
    bf16x8 af[4], bv[2];
#pragma unroll
    for (int mi = 0; mi < 4; mi++)
      af[mi] = *(const bf16x8*)&Al[wr * 64 + mi * 16 + l16][quad * 8];
#pragma unroll
    for (int nj = 0; nj < 2; nj++)
      bv[nj] = *(const bf16x8*)&Bl[wc * 32 + nj * 16 + l16][quad * 8];
#pragma unroll
    for (int mi = 0; mi < 4; mi++)
#pragma unroll
      for (int nj = 0; nj < 2; nj++)
        acc[mi][nj] = __builtin_amdgcn_mfma_f32_16x16x32_bf16(
            af[mi], bv[nj], acc[mi][nj], 0, 0, 0);
  }

#pragma unroll
  for (int mi = 0; mi < 4; mi++) {
    int ocb = oc0 + wr * 64 + mi * 16 + quad * 4;
    float4 bs4 = *(const float4*)&bias[ocb];
    float4 sc4 = {1.f, 1.f, 1.f, 1.f}, sh4 = bs4;
    if (has_bn) {
      float4 g4 = *(const float4*)&bng[ocb];
      float4 b4 = *(const float4*)&bnb[ocb];
      float4 m4 = *(const float4*)&bnm[ocb];
      float4 v4 = *(const float4*)&bnv[ocb];
      sc4.x = g4.x * rsqrtf(v4.x + EPSB); sh4.x = bs4.x * sc4.x + b4.x - m4.x * sc4.x;
      sc4.y = g4.y * rsqrtf(v4.y + EPSB); sh4.y = bs4.y * sc4.y + b4.y - m4.y * sc4.y;
      sc4.z = g4.z * rsqrtf(v4.z + EPSB); sh4.z = bs4.z * sc4.z + b4.z - m4.z * sc4.z;
      sc4.w = g4.w * rsqrtf(v4.w + EPSB); sh4.w = bs4.w * sc4.w + b4.w - m4.w * sc4.w;
    }
    float sc[4] = {sc4.x, sc4.y, sc4.z, sc4.w};
    float sh[4] = {sh4.x, sh4.y, sh4.z, sh4.w};
#pragma unroll
    for (int nj = 0; nj < 2; nj++) {
      int p = p0 + wc * 32 + nj * 16 + l16;
#pragma unroll
      for (int r = 0; r < 4; r++) {
        float val = acc[mi][nj][r] * sc[r] + sh[r];
        if (relu) val = fmaxf(val, 0.f);
        size_t gi = (((size_t)(b * 256 + ocb + r)) << 12) + p;
        if (out_bf16) ((bf16*)OutV)[gi] = __float2bfloat16(val);
        else          ((float*)OutV)[gi] = val;
      }
    }
  }
}

// ---------------- MFMA q/k GEMM (OC=32, IC=256), q & k fused via blockIdx.y
__global__ __launch_bounds__(256) void k_gemm_qk(
    const float* __restrict__ x4, const float* __restrict__ x3,
    const float* __restrict__ wq, const float* __restrict__ wk,
    const float* __restrict__ bq, const float* __restrict__ bk,
    bf16* __restrict__ qb, bf16* __restrict__ kb) {
  __shared__ __align__(16) bf16 Al[32][40];
  __shared__ __align__(16) bf16 Bl[128][40];

  int t = threadIdx.x;
  int w = t >> 6, lane = t & 63, l16 = lane & 15, quad = lane >> 4;
  int p0 = blockIdx.x * 128;
  int b = blockIdx.z;
  const float* In = (blockIdx.y == 0) ? x4 : x3;
  const float* W  = (blockIdx.y == 0) ? wq : wk;
  const float* bi = (blockIdx.y == 0) ? bq : bk;
  bf16* Out       = (blockIdx.y == 0) ? qb : kb;
  const float* Inb = In + (size_t)b * 256 * 4096;

  f32x4 acc[2][2];
#pragma unroll
  for (int mi = 0; mi < 2; mi++)
#pragma unroll
    for (int nj = 0; nj < 2; nj++) acc[mi][nj] = (f32x4){0.f, 0.f, 0.f, 0.f};

  int aocl = t >> 3, akb = (t & 7) * 4;
  int sl = t & 15, srp = t >> 4;

  for (int kc = 0; kc < 256; kc += 32) {
    __syncthreads();
    {
      const float* src = W + (size_t)aocl * 256 + kc + akb;
      float4 f0 = *(const float4*)(src);
      uint2 u = {pk2(f0.x, f0.y), pk2(f0.z, f0.w)};
      *(uint2*)&Al[aocl][akb] = u;
    }
    {
      const float* re = Inb + (size_t)(kc + 2 * srp) * 4096 + p0 + sl;
      const float* ro = re + 4096;
#pragma unroll
      for (int j = 0; j < 8; j++) {
        float e = re[j * 16];
        float o = ro[j * 16];
        *(unsigned int*)&Bl[j * 16 + sl][2 * srp] = pk2(e, o);
      }
    }
    __syncthreads();
    bf16x8 af[2], bv[2];
#pragma unroll
    for (int mi = 0; mi < 2; mi++)
      af[mi] = *(const bf16x8*)&Al[mi * 16 + l16][quad * 8];
#pragma unroll
    for (int nj = 0; nj < 2; nj++)
      bv[nj] = *(const bf16x8*)&Bl[w * 32 + nj * 16 + l16][quad * 8];
#pragma unroll
    for (int mi = 0; mi < 2; mi++)
#pragma unroll
      for (int nj = 0; nj < 2; nj++)
        acc[mi][nj] = __builtin_amdgcn_mfma_f32_16x16x32_bf16(
            af[mi], bv[nj], acc[mi][nj], 0, 0, 0);
  }

#pragma unroll
  for (int mi = 0; mi < 2; mi++) {
    int ocb = mi * 16 + quad * 4;
    float4 bs4 = *(const float4*)&bi[ocb];
    float bs[4] = {bs4.x, bs4.y, bs4.z, bs4.w};
#pragma unroll
    for (int nj = 0; nj < 2; nj++) {
      int p = p0 + w * 32 + nj * 16 + l16;
      float v0 = acc[mi][nj][0] + bs[0];
      float v1 = acc[mi][nj][1] + bs[1];
      float v2 = acc[mi][nj][2] + bs[2];
      float v3 = acc[mi][nj][3] + bs[3];
      uint2 u = {pk2(v0, v1), pk2(v2, v3)};
      *(uint2*)&Out[((size_t)(b * 4096) + p) * 32 + ocb] = u;
    }
  }
}

// ------------------------------------------- MFMA flash attention + residual
// v2: S^T = K·Q^T (packed b64 P writes); V A-frags direct from global (no Vt);
// 8 waves (512 thr); P tile XOR-swizzled 16B chunks, no padding.
// S-phase: wave w -> q-tile qt=w>>1, key-half kh=w&1.
// PV-phase: wave w -> channels w*32..+31; O'[c][q] = sum_k V[c][k] P[q][k].
__global__ __launch_bounds__(512) void k_attn_mfma(
    const bf16* __restrict__ qb, const bf16* __restrict__ kb,
    const bf16* __restrict__ vb, const float* __restrict__ x1,
    const float* __restrict__ gamma, float* __restrict__ out) {
  __shared__ __align__(16) bf16 Pl[64 * 64];   // [q][k], 16B chunk c ^ (q&7)
  __shared__ float lsumh[2][64];

  int t = threadIdx.x;
  int w = t >> 6, lane = t & 63;
  int l16 = lane & 15, quad = lane >> 4;
  int qt = w >> 1, kh = w & 1;
  int q0 = blockIdx.x * 64;
  int b = blockIdx.y;

  const bf16* kbb = kb + (size_t)b * 4096 * 32;
  const bf16* vbb = vb + (size_t)b * 256 * 4096;

  // Q as B-operand: n=l16 -> q = q0+qt*16+l16, k=quad*8+j (d-dim)
  bf16x8 qfrag = *(const bf16x8*)(qb + ((size_t)(b * 4096 + q0 + qt * 16 + l16) * 32) + quad * 8);

  f32x4 acc[2][4];   // [ci (c-tile)][nj (q-tile)]
#pragma unroll
  for (int ci = 0; ci < 2; ci++)
#pragma unroll
    for (int nj = 0; nj < 4; nj++) acc[ci][nj] = (f32x4){0.f, 0.f, 0.f, 0.f};
  float lpart = 0.f;

  int psw = (l16 & 7) << 1;          // P-write swizzle (4-elt granularity)
  int prow = (qt * 16 + l16) * 64;   // P-write row base

  for (int j0 = 0; j0 < 4096; j0 += 64) {
    // prefetch V A-frags (m=l16 -> c=w*32+ci*16+l16) and K A-frags from global
    bf16x8 vf[2][2], kf[2];
#pragma unroll
    for (int ci = 0; ci < 2; ci++)
#pragma unroll
      for (int kc = 0; kc < 2; kc++)
        vf[ci][kc] = *(const bf16x8*)(vbb + (size_t)(w * 32 + ci * 16 + l16) * 4096 +
                                      j0 + kc * 32 + quad * 8);
#pragma unroll
    for (int mi = 0; mi < 2; mi++)
      kf[mi] = *(const bf16x8*)(kbb + (size_t)(j0 + kh * 32 + mi * 16 + l16) * 32 + quad * 8);

    __syncthreads();   // previous PV reads of Pl complete
    // S^T phase: lane holds 4 consecutive keys (quad*4+r) for q=l16
#pragma unroll
    for (int mi = 0; mi < 2; mi++) {
      f32x4 s = __builtin_amdgcn_mfma_f32_16x16x32_bf16(
          kf[mi], qfrag, (f32x4){0.f, 0.f, 0.f, 0.f}, 0, 0, 0);
      float p0f = __expf(fminf(s[0], 80.f));
      float p1f = __expf(fminf(s[1], 80.f));
      float p2f = __expf(fminf(s[2], 80.f));
      float p3f = __expf(fminf(s[3], 80.f));
      lpart += (p0f + p1f) + (p2f + p3f);
      int idx4 = kh * 8 + mi * 4 + quad;
      uint2 u = {pk2(p0f, p1f), pk2(p2f, p3f)};
      *(uint2*)&Pl[prow + ((idx4 ^ psw) << 2)] = u;
    }
    __syncthreads();   // Pl ready
    // PV: O'[c][q] += V·P^T
#pragma unroll
    for (int kc = 0; kc < 2; kc++) {
      bf16x8 pf[4];
#pragma unroll
      for (int nj = 0; nj < 4; nj++)
        pf[nj] = *(const bf16x8*)&Pl[(nj * 16 + l16) * 64 +
                                     (((kc * 4 + quad) ^ (l16 & 7)) << 3)];
#pragma unroll
      for (int ci = 0; ci < 2; ci++)
#pragma unroll
        for (int nj = 0; nj < 4; nj++)
          acc[ci][nj] = __builtin_amdgcn_mfma_f32_16x16x32_bf16(
              vf[ci][kc], pf[nj], acc[ci][nj], 0, 0, 0);
    }
  }

  // softmax denominators: lane's lpart covers q=qt*16+l16, keys of (kh, quads)
  lpart += __shfl_xor(lpart, 16);
  lpart += __shfl_xor(lpart, 32);
  if (lane < 16) lsumh[kh][qt * 16 + l16] = lpart;
  __syncthreads();

  float gm = gamma[0];
#pragma unroll
  for (int nj = 0; nj < 4; nj++) {
    int ql = nj * 16 + l16;
    float linv = 1.f / (lsumh[0][ql] + lsumh[1][ql]);
    float gl = gm * linv;
#pragma unroll
    for (int ci = 0; ci < 2; ci++) {
      int cb = w * 32 + ci * 16 + quad * 4;
#pragma unroll
      for (int r = 0; r < 4; r++) {
        size_t gidx = (((size_t)(b * 256 + cb + r)) << 12) + q0 + ql;
        out[gidx] = gl * acc[ci][nj][r] + x1[gidx];
      }
    }
  }
}

// ------------------------------------------------------------------- launcher
extern "C" void kernel_launch(void* const* d_in, const int* in_sizes, int n_in,
                              void* d_out, int out_size, void* d_ws, size_t ws_size,
                              hipStream_t stream) {
  const float* x1    = (const float*)d_in[0];
  const float* x2    = (const float*)d_in[1];
  const float* w1_dw = (const float*)d_in[2];
  const float* b1_dw = (const float*)d_in[3];
  const float* w1_pw = (const float*)d_in[4];
  const float* b1_pw = (const float*)d_in[5];
  const float* bn1_g = (const float*)d_in[6];
  const float* bn1_b = (const float*)d_in[7];
  const float* bn1_m = (const float*)d_in[8];
  const float* bn1_v = (const float*)d_in[9];
  const float* w2_dw = (const float*)d_in[10];
  const float* b2_dw = (const float*)d_in[11];
  const float* w2_pw = (const float*)d_in[12];
  const float* b2_pw = (const float*)d_in[13];
  const float* bn2_g = (const float*)d_in[14];
  const float* bn2_b = (const float*)d_in[15];
  const float* bn2_m = (const float*)d_in[16];
  const float* bn2_v = (const float*)d_in[17];
  const float* wq    = (const float*)d_in[18];
  const float* bq    = (const float*)d_in[19];
  const float* wk    = (const float*)d_in[20];
  const float* bk    = (const float*)d_in[21];
  const float* wv    = (const float*)d_in[22];
  const float* bv    = (const float*)d_in[23];
  const float* gamma = (const float*)d_in[24];

  float* ws  = (float*)d_ws;
  float* sub = ws;
  float* h   = ws + 4194304;
  float* x3  = ws + 12582912;
  float* x4  = ws;
  bf16* qb  = (bf16*)(ws + 4194304);
  bf16* kbf = qb + 524288;
  bf16* vvb = kbf + 524288;

  k_sub<<<16384, 256, 0, stream>>>(x1, x2, sub);

  k_dwconv<<<32768, 256, 0, stream>>>(sub, x1, w1_dw, b1_dw, h);
  k_gemm_mfma<<<dim3(64, 2, 4), 256, 0, stream>>>(h, w1_pw, b1_pw, bn1_g, bn1_b,
                                                  bn1_m, bn1_v, 1, 1, 0, x3, 512);
  k_dwconv<<<32768, 256, 0, stream>>>(sub, x2, w2_dw, b2_dw, h);
  k_gemm_mfma<<<dim3(64, 2, 4), 256, 0, stream>>>(h, w2_pw, b2_pw, bn2_g, bn2_b,
                                                  bn2_m, bn2_v, 1, 1, 0, x4, 512);

  k_gemm_qk<<<dim3(32, 2, 4), 256, 0, stream>>>(x4, x3, wq, wk, bq, bk, qb, kbf);
  k_gemm_mfma<<<dim3(64, 2, 4), 256, 0, stream>>>(x3, wv, bv, nullptr, nullptr,
                                                  nullptr, nullptr, 0, 0, 1, vvb, 256);

  k_attn_mfma<<<dim3(64, 4), 512, 0, stream>>>(qb, kbf, vvb, x1, gamma, (float*)d_out);
}

// Round 6
// 383.394 us; speedup vs baseline: 1.0361x; 1.0361x over previous
//
#include <hip/hip_runtime.h>
#include <hip/hip_bf16.h>

#define EPSB 1e-5f

typedef __hip_bfloat16 bf16;
typedef __attribute__((ext_vector_type(8))) short bf16x8;
typedef __attribute__((ext_vector_type(4))) float f32x4;

__device__ __forceinline__ unsigned short f2bu(float x) {
  bf16 h = __float2bfloat16(x);
  return *reinterpret_cast<unsigned short*>(&h);
}
__device__ __forceinline__ unsigned int pk2(float lo, float hi) {
  return ((unsigned int)f2bu(hi) << 16) | (unsigned int)f2bu(lo);
}

// ---------------------------------------------------------------- sub = x1-x2
__global__ __launch_bounds__(256) void k_sub(const float* __restrict__ x1,
                                             const float* __restrict__ x2,
                                             float* __restrict__ sub) {
  int i = blockIdx.x * 256 + threadIdx.x;
  sub[i] = x1[i] - x2[i];
}

// ------------------------------------------- grouped 3x3 conv (2 in ch/group)
__global__ __launch_bounds__(256) void k_dwconv(const float* __restrict__ sub,
                                                const float* __restrict__ xs,
                                                const float* __restrict__ w,
                                                const float* __restrict__ bias,
                                                float* __restrict__ h) {
  int idx = blockIdx.x * 256 + threadIdx.x;   // 4*512*4096
  int pix = idx & 4095;
  int o   = (idx >> 12) & 511;
  int b   = idx >> 21;
  int y = pix >> 6, x = pix & 63;
  float wr[18];
  const float* wp = w + o * 18;
#pragma unroll
  for (int i = 0; i < 18; i++) wr[i] = wp[i];
  float acc = bias[o];
  int cbase = (o & ~1) & 255;
  bool use_sub = (o < 256);
  const float* s0 = (use_sub ? sub : xs) + ((size_t)(b * 256 + cbase) << 12);
#pragma unroll
  for (int ky = 0; ky < 3; ky++) {
    int yy = y + ky - 1;
    if (yy < 0 || yy > 63) continue;
#pragma unroll
    for (int kx = 0; kx < 3; kx++) {
      int xx = x + kx - 1;
      if (xx < 0 || xx > 63) continue;
      int off = yy * 64 + xx;
      acc += wr[ky * 3 + kx] * s0[off] + wr[9 + ky * 3 + kx] * s0[4096 + off];
    }
  }
  h[idx] = acc;
}

// --------------------- MFMA 1x1-conv GEMM (OC=256): Out[oc,p] = W[oc,:]@In[:,p]
__global__ __launch_bounds__(256) void k_gemm_mfma(
    const float* __restrict__ In, const float* __restrict__ W,
    const float* __restrict__ bias,
    const float* __restrict__ bng, const float* __restrict__ bnb,
    const float* __restrict__ bnm, const float* __restrict__ bnv,
    int has_bn, int relu, int out_bf16,
    void* __restrict__ OutV, int IC) {
  __shared__ __align__(16) bf16 Al[128][40];   // [oc][k]
  __shared__ __align__(16) bf16 Bl[64][40];    // [p][k]

  int t = threadIdx.x;
  int w = t >> 6, lane = t & 63, l16 = lane & 15, quad = lane >> 4;
  int wr = w >> 1, wc = w & 1;
  int p0 = blockIdx.x * 64;
  int oc0 = blockIdx.y * 128;
  int b = blockIdx.z;
  const float* Inb = In + (size_t)b * IC * 4096;

  f32x4 acc[4][2];
#pragma unroll
  for (int mi = 0; mi < 4; mi++)
#pragma unroll
    for (int nj = 0; nj < 2; nj++) acc[mi][nj] = (f32x4){0.f, 0.f, 0.f, 0.f};

  int sl = t & 15, srp = t >> 4;
  int ocl = t >> 1, kb = (t & 1) * 16;

  for (int kc = 0; kc < IC; kc += 32) {
    __syncthreads();
    {   // stage A: 128oc x 32k
      const float* src = W + (size_t)(oc0 + ocl) * IC + kc + kb;
      float4 f0 = *(const float4*)(src);
      float4 f1 = *(const float4*)(src + 4);
      float4 f2 = *(const float4*)(src + 8);
      float4 f3 = *(const float4*)(src + 12);
      uint4 u0 = {pk2(f0.x, f0.y), pk2(f0.z, f0.w), pk2(f1.x, f1.y), pk2(f1.z, f1.w)};
      uint4 u1 = {pk2(f2.x, f2.y), pk2(f2.z, f2.w), pk2(f3.x, f3.y), pk2(f3.z, f3.w)};
      *(uint4*)&Al[ocl][kb] = u0;
      *(uint4*)&Al[ocl][kb + 8] = u1;
    }
    {   // stage B: 32k x 64p transpose
      const float* re = Inb + (size_t)(kc + 2 * srp) * 4096 + p0 + sl;
      const float* ro = re + 4096;
#pragma unroll
      for (int j = 0; j < 4; j++) {
        float e = re[j * 16];
        float o = ro[j * 16];
        *(unsigned int*)&Bl[j * 16 + sl][2 * srp] = pk2(e, o);
      }
    }
    __syncthreads();
    bf16x8 af[4], bv[2];
#pragma unroll
    for (int mi = 0; mi < 4; mi++)
      af[mi] = *(const bf16x8*)&Al[wr * 64 + mi * 16 + l16][quad * 8];
#pragma unroll
    for (int nj = 0; nj < 2; nj++)
      bv[nj] = *(const bf16x8*)&Bl[wc * 32 + nj * 16 + l16][quad * 8];
#pragma unroll
    for (int mi = 0; mi < 4; mi++)
#pragma unroll
      for (int nj = 0; nj < 2; nj++)
        acc[mi][nj] = __builtin_amdgcn_mfma_f32_16x16x32_bf16(
            af[mi], bv[nj], acc[mi][nj], 0, 0, 0);
  }

#pragma unroll
  for (int mi = 0; mi < 4; mi++) {
    int ocb = oc0 + wr * 64 + mi * 16 + quad * 4;
    float4 bs4 = *(const float4*)&bias[ocb];
    float4 sc4 = {1.f, 1.f, 1.f, 1.f}, sh4 = bs4;
    if (has_bn) {
      float4 g4 = *(const float4*)&bng[ocb];
      float4 b4 = *(const float4*)&bnb[ocb];
      float4 m4 = *(const float4*)&bnm[ocb];
      float4 v4 = *(const float4*)&bnv[ocb];
      sc4.x = g4.x * rsqrtf(v4.x + EPSB); sh4.x = bs4.x * sc4.x + b4.x - m4.x * sc4.x;
      sc4.y = g4.y * rsqrtf(v4.y + EPSB); sh4.y = bs4.y * sc4.y + b4.y - m4.y * sc4.y;
      sc4.z = g4.z * rsqrtf(v4.z + EPSB); sh4.z = bs4.z * sc4.z + b4.z - m4.z * sc4.z;
      sc4.w = g4.w * rsqrtf(v4.w + EPSB); sh4.w = bs4.w * sc4.w + b4.w - m4.w * sc4.w;
    }
    float sc[4] = {sc4.x, sc4.y, sc4.z, sc4.w};
    float sh[4] = {sh4.x, sh4.y, sh4.z, sh4.w};
#pragma unroll
    for (int nj = 0; nj < 2; nj++) {
      int p = p0 + wc * 32 + nj * 16 + l16;
#pragma unroll
      for (int r = 0; r < 4; r++) {
        float val = acc[mi][nj][r] * sc[r] + sh[r];
        if (relu) val = fmaxf(val, 0.f);
        size_t gi = (((size_t)(b * 256 + ocb + r)) << 12) + p;
        if (out_bf16) ((bf16*)OutV)[gi] = __float2bfloat16(val);
        else          ((float*)OutV)[gi] = val;
      }
    }
  }
}

// ---------------- MFMA q/k GEMM (OC=32, IC=256), q & k fused via blockIdx.y
__global__ __launch_bounds__(256) void k_gemm_qk(
    const float* __restrict__ x4, const float* __restrict__ x3,
    const float* __restrict__ wq, const float* __restrict__ wk,
    const float* __restrict__ bq, const float* __restrict__ bk,
    bf16* __restrict__ qb, bf16* __restrict__ kb) {
  __shared__ __align__(16) bf16 Al[32][40];
  __shared__ __align__(16) bf16 Bl[128][40];

  int t = threadIdx.x;
  int w = t >> 6, lane = t & 63, l16 = lane & 15, quad = lane >> 4;
  int p0 = blockIdx.x * 128;
  int b = blockIdx.z;
  const float* In = (blockIdx.y == 0) ? x4 : x3;
  const float* W  = (blockIdx.y == 0) ? wq : wk;
  const float* bi = (blockIdx.y == 0) ? bq : bk;
  bf16* Out       = (blockIdx.y == 0) ? qb : kb;
  const float* Inb = In + (size_t)b * 256 * 4096;

  f32x4 acc[2][2];
#pragma unroll
  for (int mi = 0; mi < 2; mi++)
#pragma unroll
    for (int nj = 0; nj < 2; nj++) acc[mi][nj] = (f32x4){0.f, 0.f, 0.f, 0.f};

  int aocl = t >> 3, akb = (t & 7) * 4;
  int sl = t & 15, srp = t >> 4;

  for (int kc = 0; kc < 256; kc += 32) {
    __syncthreads();
    {
      const float* src = W + (size_t)aocl * 256 + kc + akb;
      float4 f0 = *(const float4*)(src);
      uint2 u = {pk2(f0.x, f0.y), pk2(f0.z, f0.w)};
      *(uint2*)&Al[aocl][akb] = u;
    }
    {
      const float* re = Inb + (size_t)(kc + 2 * srp) * 4096 + p0 + sl;
      const float* ro = re + 4096;
#pragma unroll
      for (int j = 0; j < 8; j++) {
        float e = re[j * 16];
        float o = ro[j * 16];
        *(unsigned int*)&Bl[j * 16 + sl][2 * srp] = pk2(e, o);
      }
    }
    __syncthreads();
    bf16x8 af[2], bv[2];
#pragma unroll
    for (int mi = 0; mi < 2; mi++)
      af[mi] = *(const bf16x8*)&Al[mi * 16 + l16][quad * 8];
#pragma unroll
    for (int nj = 0; nj < 2; nj++)
      bv[nj] = *(const bf16x8*)&Bl[w * 32 + nj * 16 + l16][quad * 8];
#pragma unroll
    for (int mi = 0; mi < 2; mi++)
#pragma unroll
      for (int nj = 0; nj < 2; nj++)
        acc[mi][nj] = __builtin_amdgcn_mfma_f32_16x16x32_bf16(
            af[mi], bv[nj], acc[mi][nj], 0, 0, 0);
  }

#pragma unroll
  for (int mi = 0; mi < 2; mi++) {
    int ocb = mi * 16 + quad * 4;
    float4 bs4 = *(const float4*)&bi[ocb];
    float bs[4] = {bs4.x, bs4.y, bs4.z, bs4.w};
#pragma unroll
    for (int nj = 0; nj < 2; nj++) {
      int p = p0 + w * 32 + nj * 16 + l16;
      float v0 = acc[mi][nj][0] + bs[0];
      float v1 = acc[mi][nj][1] + bs[1];
      float v2 = acc[mi][nj][2] + bs[2];
      float v3 = acc[mi][nj][3] + bs[3];
      uint2 u = {pk2(v0, v1), pk2(v2, v3)};
      *(uint2*)&Out[((size_t)(b * 4096) + p) * 32 + ocb] = u;
    }
  }
}

// ------------------------------------------- MFMA flash attention + residual
// v3: 128-key iterations, ONE barrier per iteration (double-buffered P),
// loads for iter i+1 issued right after barrier_i and hidden under PV+S MFMA.
// S-phase: wave w owns keys w*16..+16 for ALL 64 q (4 Q B-frags in regs).
// PV-phase: wave w owns channels w*32..+31. P tile XOR-swizzled 16B chunks.
__global__ __launch_bounds__(512) void k_attn_mfma(
    const bf16* __restrict__ qb, const bf16* __restrict__ kb,
    const bf16* __restrict__ vb, const float* __restrict__ x1,
    const float* __restrict__ gamma, float* __restrict__ out) {
  __shared__ __align__(16) bf16 Pl[2][64 * 128];   // [q][k] per buffer
  __shared__ float lsumw[8][64];

  int t = threadIdx.x;
  int w = t >> 6, lane = t & 63;
  int l16 = lane & 15, quad = lane >> 4;
  int q0 = blockIdx.x * 64;
  int b = blockIdx.y;

  const bf16* kbb = kb + (size_t)b * 4096 * 32;
  const bf16* vbb = vb + (size_t)b * 256 * 4096;

  // Q B-frags for all 4 q-tiles (n=l16 -> q=q0+nj*16+l16, k=quad*8+j)
  bf16x8 qf[4];
#pragma unroll
  for (int nj = 0; nj < 4; nj++)
    qf[nj] = *(const bf16x8*)(qb + ((size_t)(b * 4096 + q0 + nj * 16 + l16)) * 32 + quad * 8);

  f32x4 acc[2][4];
#pragma unroll
  for (int ci = 0; ci < 2; ci++)
#pragma unroll
    for (int nj = 0; nj < 4; nj++) acc[ci][nj] = (f32x4){0.f, 0.f, 0.f, 0.f};
  float lpart[4] = {0.f, 0.f, 0.f, 0.f};

  const bf16* kptr = kbb + ((size_t)(w * 16 + l16)) * 32 + quad * 8;   // + j0*32
  const bf16* vptr = vbb + ((size_t)(w * 32 + l16)) * 4096 + quad * 8; // + ci*16*4096 + j0 + kc*32

  // c16 write chunk for P: key-local = w*16+quad*4 -> chunk = w*2+(quad>>1)
  int c16w = w * 2 + (quad >> 1);
  int off8 = (quad & 1) * 4;

  auto load_kv = [&](int j0, bf16x8& kf, bf16x8 vf[2][4]) {
    kf = *(const bf16x8*)(kptr + (size_t)j0 * 32);
#pragma unroll
    for (int ci = 0; ci < 2; ci++)
#pragma unroll
      for (int kc = 0; kc < 4; kc++)
        vf[ci][kc] = *(const bf16x8*)(vptr + (size_t)ci * 16 * 4096 + j0 + kc * 32);
  };

  auto s_phase = [&](const bf16x8& kf, int pb) {
    bf16* P = Pl[pb];
#pragma unroll
    for (int nj = 0; nj < 4; nj++) {
      f32x4 s = __builtin_amdgcn_mfma_f32_16x16x32_bf16(
          kf, qf[nj], (f32x4){0.f, 0.f, 0.f, 0.f}, 0, 0, 0);
      float p0f = __expf(fminf(s[0], 80.f));
      float p1f = __expf(fminf(s[1], 80.f));
      float p2f = __expf(fminf(s[2], 80.f));
      float p3f = __expf(fminf(s[3], 80.f));
      lpart[nj] += (p0f + p1f) + (p2f + p3f);
      int row = nj * 16 + l16;
      int c16 = c16w ^ (row & 15);
      uint2 u = {pk2(p0f, p1f), pk2(p2f, p3f)};
      *(uint2*)&P[row * 128 + c16 * 8 + off8] = u;
    }
  };

  auto pv_phase = [&](const bf16x8 vf[2][4], int pb) {
    const bf16* P = Pl[pb];
#pragma unroll
    for (int kc = 0; kc < 4; kc++) {
      bf16x8 pf[4];
#pragma unroll
      for (int nj = 0; nj < 4; nj++) {
        int row = nj * 16 + l16;
        int c16 = (kc * 4 + quad) ^ (row & 15);
        pf[nj] = *(const bf16x8*)&P[row * 128 + c16 * 8];
      }
#pragma unroll
      for (int ci = 0; ci < 2; ci++)
#pragma unroll
        for (int nj = 0; nj < 4; nj++)
          acc[ci][nj] = __builtin_amdgcn_mfma_f32_16x16x32_bf16(
              vf[ci][kc], pf[nj], acc[ci][nj], 0, 0, 0);
    }
  };

  bf16x8 kfA, kfB, vfA[2][4], vfB[2][4];
  load_kv(0, kfA, vfA);
  s_phase(kfA, 0);

  for (int i = 0; i < 32; i += 2) {
    __syncthreads();
    if (i < 31) load_kv((i + 1) * 128, kfB, vfB);
    pv_phase(vfA, 0);
    if (i < 31) s_phase(kfB, 1);
    __syncthreads();
    if (i + 2 < 32) load_kv((i + 2) * 128, kfA, vfA);
    if (i + 1 < 32) pv_phase(vfB, 1);
    if (i + 2 < 32) s_phase(kfA, 0);
  }

  // softmax denominators: lane's lpart[nj] covers q=nj*16+l16, keys of (w,quad)
#pragma unroll
  for (int nj = 0; nj < 4; nj++) {
    float v = lpart[nj];
    v += __shfl_xor(v, 16);
    v += __shfl_xor(v, 32);
    lpart[nj] = v;
  }
  if (lane < 16) {
#pragma unroll
    for (int nj = 0; nj < 4; nj++) lsumw[w][nj * 16 + lane] = lpart[nj];
  }
  __syncthreads();

  float gm = gamma[0];
#pragma unroll
  for (int nj = 0; nj < 4; nj++) {
    int ql = nj * 16 + l16;
    float ls = 0.f;
#pragma unroll
    for (int w8 = 0; w8 < 8; w8++) ls += lsumw[w8][ql];
    float gl = gm / ls;
#pragma unroll
    for (int ci = 0; ci < 2; ci++) {
      int cb = w * 32 + ci * 16 + quad * 4;
#pragma unroll
      for (int r = 0; r < 4; r++) {
        size_t gidx = (((size_t)(b * 256 + cb + r)) << 12) + q0 + ql;
        out[gidx] = gl * acc[ci][nj][r] + x1[gidx];
      }
    }
  }
}

// ------------------------------------------------------------------- launcher
extern "C" void kernel_launch(void* const* d_in, const int* in_sizes, int n_in,
                              void* d_out, int out_size, void* d_ws, size_t ws_size,
                              hipStream_t stream) {
  const float* x1    = (const float*)d_in[0];
  const float* x2    = (const float*)d_in[1];
  const float* w1_dw = (const float*)d_in[2];
  const float* b1_dw = (const float*)d_in[3];
  const float* w1_pw = (const float*)d_in[4];
  const float* b1_pw = (const float*)d_in[5];
  const float* bn1_g = (const float*)d_in[6];
  const float* bn1_b = (const float*)d_in[7];
  const float* bn1_m = (const float*)d_in[8];
  const float* bn1_v = (const float*)d_in[9];
  const float* w2_dw = (const float*)d_in[10];
  const float* b2_dw = (const float*)d_in[11];
  const float* w2_pw = (const float*)d_in[12];
  const float* b2_pw = (const float*)d_in[13];
  const float* bn2_g = (const float*)d_in[14];
  const float* bn2_b = (const float*)d_in[15];
  const float* bn2_m = (const float*)d_in[16];
  const float* bn2_v = (const float*)d_in[17];
  const float* wq    = (const float*)d_in[18];
  const float* bq    = (const float*)d_in[19];
  const float* wk    = (const float*)d_in[20];
  const float* bk    = (const float*)d_in[21];
  const float* wv    = (const float*)d_in[22];
  const float* bv    = (const float*)d_in[23];
  const float* gamma = (const float*)d_in[24];

  float* ws  = (float*)d_ws;
  float* sub = ws;
  float* h   = ws + 4194304;
  float* x3  = ws + 12582912;
  float* x4  = ws;
  bf16* qb  = (bf16*)(ws + 4194304);
  bf16* kbf = qb + 524288;
  bf16* vvb = kbf + 524288;

  k_sub<<<16384, 256, 0, stream>>>(x1, x2, sub);

  k_dwconv<<<32768, 256, 0, stream>>>(sub, x1, w1_dw, b1_dw, h);
  k_gemm_mfma<<<dim3(64, 2, 4), 256, 0, stream>>>(h, w1_pw, b1_pw, bn1_g, bn1_b,
                                                  bn1_m, bn1_v, 1, 1, 0, x3, 512);
  k_dwconv<<<32768, 256, 0, stream>>>(sub, x2, w2_dw, b2_dw, h);
  k_gemm_mfma<<<dim3(64, 2, 4), 256, 0, stream>>>(h, w2_pw, b2_pw, bn2_g, bn2_b,
                                                  bn2_m, bn2_v, 1, 1, 0, x4, 512);

  k_gemm_qk<<<dim3(32, 2, 4), 256, 0, stream>>>(x4, x3, wq, wk, bq, bk, qb, kbf);
  k_gemm_mfma<<<dim3(64, 2, 4), 256, 0, stream>>>(x3, wv, bv, nullptr, nullptr,
                                                  nullptr, nullptr, 0, 0, 1, vvb, 256);

  k_attn_mfma<<<dim3(64, 4), 512, 0, stream>>>(qb, kbf, vvb, x1, gamma, (float*)d_out);
}

// Round 7
// 362.353 us; speedup vs baseline: 1.0962x; 1.0581x over previous
//
#include <hip/hip_runtime.h>
#include <hip/hip_bf16.h>

#define EPSB 1e-5f

typedef __hip_bfloat16 bf16;
typedef __attribute__((ext_vector_type(8))) short bf16x8;
typedef __attribute__((ext_vector_type(4))) float f32x4;

__device__ __forceinline__ unsigned short f2bu(float x) {
  bf16 h = __float2bfloat16(x);
  return *reinterpret_cast<unsigned short*>(&h);
}
__device__ __forceinline__ unsigned int pk2(float lo, float hi) {
  return ((unsigned int)f2bu(hi) << 16) | (unsigned int)f2bu(lo);
}

// ------------------------- fused (sub|x) grouped 3x3 conv, tiled, bf16 output
// block = (group g 0..255, batch b). in-channels: g<128 -> x1-x2 (ch 2g,2g+1),
// g>=128 -> xs (ch 2(g-128),+1). out-channels 2g, 2g+1 -> h[b][o][4096] bf16.
__global__ __launch_bounds__(256) void k_dwconv2(
    const float* __restrict__ x1, const float* __restrict__ x2,
    const float* __restrict__ xs, const float* __restrict__ w,
    const float* __restrict__ bias, bf16* __restrict__ h) {
  __shared__ float img[2 * 64 * 64];
  int g = blockIdx.x, b = blockIdx.y;
  int t = threadIdx.x;

  if (g < 128) {
    const float4* p1 = (const float4*)(x1 + ((size_t)(b * 256 + 2 * g) << 12));
    const float4* p2 = (const float4*)(x2 + ((size_t)(b * 256 + 2 * g) << 12));
#pragma unroll
    for (int u = 0; u < 8; u++) {
      int i = u * 256 + t;
      float4 a = p1[i], c = p2[i];
      float4 d = {a.x - c.x, a.y - c.y, a.z - c.z, a.w - c.w};
      ((float4*)img)[i] = d;
    }
  } else {
    const float4* p1 = (const float4*)(xs + ((size_t)(b * 256 + 2 * (g - 128)) << 12));
#pragma unroll
    for (int u = 0; u < 8; u++) {
      int i = u * 256 + t;
      ((float4*)img)[i] = p1[i];
    }
  }
  __syncthreads();

  int row = t >> 2, x0 = (t & 3) * 16;
  const float* wp = w + (size_t)(2 * g) * 18;   // [o0: ch0 9, ch1 9][o1: ...]
  float o0[16], o1[16];
  float bs0 = bias[2 * g], bs1 = bias[2 * g + 1];
#pragma unroll
  for (int i = 0; i < 16; i++) { o0[i] = bs0; o1[i] = bs1; }

#pragma unroll
  for (int ch = 0; ch < 2; ch++) {
    float wa[9], wb[9];
#pragma unroll
    for (int i = 0; i < 9; i++) { wa[i] = wp[ch * 9 + i]; wb[i] = wp[18 + ch * 9 + i]; }
    const float* ib = img + ch * 4096;
#pragma unroll
    for (int ky = 0; ky < 3; ky++) {
      int yy = row + ky - 1;
      if (yy < 0 || yy > 63) continue;
      float v[18];
#pragma unroll
      for (int c = 0; c < 18; c++) {
        int xx = x0 + c - 1;
        v[c] = (xx >= 0 && xx < 64) ? ib[yy * 64 + xx] : 0.f;
      }
      float a0 = wa[ky * 3], a1 = wa[ky * 3 + 1], a2 = wa[ky * 3 + 2];
      float c0 = wb[ky * 3], c1 = wb[ky * 3 + 1], c2 = wb[ky * 3 + 2];
#pragma unroll
      for (int i = 0; i < 16; i++) {
        o0[i] += a0 * v[i] + a1 * v[i + 1] + a2 * v[i + 2];
        o1[i] += c0 * v[i] + c1 * v[i + 1] + c2 * v[i + 2];
      }
    }
  }

  size_t base = (((size_t)(b * 512 + 2 * g)) << 12) + row * 64 + x0;
  uint4 u0 = {pk2(o0[0], o0[1]), pk2(o0[2], o0[3]), pk2(o0[4], o0[5]), pk2(o0[6], o0[7])};
  uint4 u1 = {pk2(o0[8], o0[9]), pk2(o0[10], o0[11]), pk2(o0[12], o0[13]), pk2(o0[14], o0[15])};
  *(uint4*)&h[base] = u0;
  *(uint4*)&h[base + 8] = u1;
  uint4 w0 = {pk2(o1[0], o1[1]), pk2(o1[2], o1[3]), pk2(o1[4], o1[5]), pk2(o1[6], o1[7])};
  uint4 w1 = {pk2(o1[8], o1[9]), pk2(o1[10], o1[11]), pk2(o1[12], o1[13]), pk2(o1[14], o1[15])};
  *(uint4*)&h[base + 4096] = w0;
  *(uint4*)&h[base + 4096 + 8] = w1;
}

// --------------- MFMA 1x1-conv GEMM (OC=256): Out[oc,p] = W[oc,:]@In[:,p]
// In bf16 [IC][4096], W fp32, Out bf16 [256][4096]. tile 128oc x 64p, BK=32.
__global__ __launch_bounds__(256) void k_gemm_mfma(
    const bf16* __restrict__ In, const float* __restrict__ W,
    const float* __restrict__ bias,
    const float* __restrict__ bng, const float* __restrict__ bnb,
    const float* __restrict__ bnm, const float* __restrict__ bnv,
    int has_bn, int relu,
    bf16* __restrict__ Out, int IC) {
  __shared__ __align__(16) bf16 Al[128][40];   // [oc][k]
  __shared__ __align__(16) bf16 Bl[64][40];    // [p][k]

  int t = threadIdx.x;
  int w = t >> 6, lane = t & 63, l16 = lane & 15, quad = lane >> 4;
  int wr = w >> 1, wc = w & 1;
  int p0 = blockIdx.x * 64;
  int oc0 = blockIdx.y * 128;
  int b = blockIdx.z;
  const bf16* Inb = In + (size_t)b * IC * 4096;

  f32x4 acc[4][2];
#pragma unroll
  for (int mi = 0; mi < 4; mi++)
#pragma unroll
    for (int nj = 0; nj < 2; nj++) acc[mi][nj] = (f32x4){0.f, 0.f, 0.f, 0.f};

  int sl = t & 15, srp = t >> 4;
  int ocl = t >> 1, kb = (t & 1) * 16;

  for (int kc = 0; kc < IC; kc += 32) {
    __syncthreads();
    {   // stage A: 128oc x 32k (fp32 W -> bf16)
      const float* src = W + (size_t)(oc0 + ocl) * IC + kc + kb;
      float4 f0 = *(const float4*)(src);
      float4 f1 = *(const float4*)(src + 4);
      float4 f2 = *(const float4*)(src + 8);
      float4 f3 = *(const float4*)(src + 12);
      uint4 u0 = {pk2(f0.x, f0.y), pk2(f0.z, f0.w), pk2(f1.x, f1.y), pk2(f1.z, f1.w)};
      uint4 u1 = {pk2(f2.x, f2.y), pk2(f2.z, f2.w), pk2(f3.x, f3.y), pk2(f3.z, f3.w)};
      *(uint4*)&Al[ocl][kb] = u0;
      *(uint4*)&Al[ocl][kb + 8] = u1;
    }
    {   // stage B: 32k x 64p transpose (bf16 bit-moves, no conversion)
      const unsigned short* re = (const unsigned short*)(Inb + (size_t)(kc + 2 * srp) * 4096 + p0 + sl);
#pragma unroll
      for (int j = 0; j < 4; j++) {
        unsigned int e = re[j * 16];
        unsigned int o = re[4096 + j * 16];
        *(unsigned int*)&Bl[j * 16 + sl][2 * srp] = e | (o << 16);
      }
    }
    __syncthreads();
    bf16x8 af[4], bv[2];
#pragma unroll
    for (int mi = 0; mi < 4; mi++)
      af[mi] = *(const bf16x8*)&Al[wr * 64 + mi * 16 + l16][quad * 8];
#pragma unroll
    for (int nj = 0; nj < 2; nj++)
      bv[nj] = *(const bf16x8*)&Bl[wc * 32 + nj * 16 + l16][quad * 8];
#pragma unroll
    for (int mi = 0; mi < 4; mi++)
#pragma unroll
      for (int nj = 0; nj < 2; nj++)
        acc[mi][nj] = __builtin_amdgcn_mfma_f32_16x16x32_bf16(
            af[mi], bv[nj], acc[mi][nj], 0, 0, 0);
  }

#pragma unroll
  for (int mi = 0; mi < 4; mi++) {
    int ocb = oc0 + wr * 64 + mi * 16 + quad * 4;
    float4 bs4 = *(const float4*)&bias[ocb];
    float4 sc4 = {1.f, 1.f, 1.f, 1.f}, sh4 = bs4;
    if (has_bn) {
      float4 g4 = *(const float4*)&bng[ocb];
      float4 b4 = *(const float4*)&bnb[ocb];
      float4 m4 = *(const float4*)&bnm[ocb];
      float4 v4 = *(const float4*)&bnv[ocb];
      sc4.x = g4.x * rsqrtf(v4.x + EPSB); sh4.x = bs4.x * sc4.x + b4.x - m4.x * sc4.x;
      sc4.y = g4.y * rsqrtf(v4.y + EPSB); sh4.y = bs4.y * sc4.y + b4.y - m4.y * sc4.y;
      sc4.z = g4.z * rsqrtf(v4.z + EPSB); sh4.z = bs4.z * sc4.z + b4.z - m4.z * sc4.z;
      sc4.w = g4.w * rsqrtf(v4.w + EPSB); sh4.w = bs4.w * sc4.w + b4.w - m4.w * sc4.w;
    }
    float sc[4] = {sc4.x, sc4.y, sc4.z, sc4.w};
    float sh[4] = {sh4.x, sh4.y, sh4.z, sh4.w};
#pragma unroll
    for (int nj = 0; nj < 2; nj++) {
      int p = p0 + wc * 32 + nj * 16 + l16;
#pragma unroll
      for (int r = 0; r < 4; r++) {
        float val = acc[mi][nj][r] * sc[r] + sh[r];
        if (relu) val = fmaxf(val, 0.f);
        Out[(((size_t)(b * 256 + ocb + r)) << 12) + p] = __float2bfloat16(val);
      }
    }
  }
}

// ---------------- MFMA q/k GEMM (OC=32, IC=256), q & k fused via blockIdx.y
// In bf16, out transposed [b][p][32] bf16
__global__ __launch_bounds__(256) void k_gemm_qk(
    const bf16* __restrict__ x4, const bf16* __restrict__ x3,
    const float* __restrict__ wq, const float* __restrict__ wk,
    const float* __restrict__ bq, const float* __restrict__ bk,
    bf16* __restrict__ qb, bf16* __restrict__ kb) {
  __shared__ __align__(16) bf16 Al[32][40];
  __shared__ __align__(16) bf16 Bl[128][40];

  int t = threadIdx.x;
  int w = t >> 6, lane = t & 63, l16 = lane & 15, quad = lane >> 4;
  int p0 = blockIdx.x * 128;
  int b = blockIdx.z;
  const bf16* In  = (blockIdx.y == 0) ? x4 : x3;
  const float* W  = (blockIdx.y == 0) ? wq : wk;
  const float* bi = (blockIdx.y == 0) ? bq : bk;
  bf16* Out       = (blockIdx.y == 0) ? qb : kb;
  const bf16* Inb = In + (size_t)b * 256 * 4096;

  f32x4 acc[2][2];
#pragma unroll
  for (int mi = 0; mi < 2; mi++)
#pragma unroll
    for (int nj = 0; nj < 2; nj++) acc[mi][nj] = (f32x4){0.f, 0.f, 0.f, 0.f};

  int aocl = t >> 3, akb = (t & 7) * 4;
  int sl = t & 15, srp = t >> 4;

  for (int kc = 0; kc < 256; kc += 32) {
    __syncthreads();
    {
      const float* src = W + (size_t)aocl * 256 + kc + akb;
      float4 f0 = *(const float4*)(src);
      uint2 u = {pk2(f0.x, f0.y), pk2(f0.z, f0.w)};
      *(uint2*)&Al[aocl][akb] = u;
    }
    {
      const unsigned short* re = (const unsigned short*)(Inb + (size_t)(kc + 2 * srp) * 4096 + p0 + sl);
#pragma unroll
      for (int j = 0; j < 8; j++) {
        unsigned int e = re[j * 16];
        unsigned int o = re[4096 + j * 16];
        *(unsigned int*)&Bl[j * 16 + sl][2 * srp] = e | (o << 16);
      }
    }
    __syncthreads();
    bf16x8 af[2], bv[2];
#pragma unroll
    for (int mi = 0; mi < 2; mi++)
      af[mi] = *(const bf16x8*)&Al[mi * 16 + l16][quad * 8];
#pragma unroll
    for (int nj = 0; nj < 2; nj++)
      bv[nj] = *(const bf16x8*)&Bl[w * 32 + nj * 16 + l16][quad * 8];
#pragma unroll
    for (int mi = 0; mi < 2; mi++)
#pragma unroll
      for (int nj = 0; nj < 2; nj++)
        acc[mi][nj] = __builtin_amdgcn_mfma_f32_16x16x32_bf16(
            af[mi], bv[nj], acc[mi][nj], 0, 0, 0);
  }

#pragma unroll
  for (int mi = 0; mi < 2; mi++) {
    int ocb = mi * 16 + quad * 4;
    float4 bs4 = *(const float4*)&bi[ocb];
    float bs[4] = {bs4.x, bs4.y, bs4.z, bs4.w};
#pragma unroll
    for (int nj = 0; nj < 2; nj++) {
      int p = p0 + w * 32 + nj * 16 + l16;
      float v0 = acc[mi][nj][0] + bs[0];
      float v1 = acc[mi][nj][1] + bs[1];
      float v2 = acc[mi][nj][2] + bs[2];
      float v3 = acc[mi][nj][3] + bs[3];
      uint2 u = {pk2(v0, v1), pk2(v2, v3)};
      *(uint2*)&Out[((size_t)(b * 4096) + p) * 32 + ocb] = u;
    }
  }
}

// ------------------------------------------- MFMA flash attention + residual
// v4: 32-q blocks -> grid (128,B) = 2 blocks/CU for cross-block overlap.
// 128-key iterations, one barrier per iter (double-buffered P).
// S-phase: wave w owns keys w*16..+16 for all 32 q (2 Q B-frags in regs).
// PV-phase: wave w owns channels w*32..+31. P XOR-swizzled 16B chunks.
__global__ __launch_bounds__(512) void k_attn_mfma(
    const bf16* __restrict__ qb, const bf16* __restrict__ kb,
    const bf16* __restrict__ vb, const float* __restrict__ x1,
    const float* __restrict__ gamma, float* __restrict__ out) {
  __shared__ __align__(16) bf16 Pl[2][32 * 128];
  __shared__ float lsumw[8][32];

  int t = threadIdx.x;
  int w = t >> 6, lane = t & 63;
  int l16 = lane & 15, quad = lane >> 4;
  int q0 = blockIdx.x * 32;
  int b = blockIdx.y;

  const bf16* kbb = kb + (size_t)b * 4096 * 32;
  const bf16* vbb = vb + (size_t)b * 256 * 4096;

  bf16x8 qf[2];
#pragma unroll
  for (int nj = 0; nj < 2; nj++)
    qf[nj] = *(const bf16x8*)(qb + ((size_t)(b * 4096 + q0 + nj * 16 + l16)) * 32 + quad * 8);

  f32x4 acc[2][2];
#pragma unroll
  for (int ci = 0; ci < 2; ci++)
#pragma unroll
    for (int nj = 0; nj < 2; nj++) acc[ci][nj] = (f32x4){0.f, 0.f, 0.f, 0.f};
  float lpart[2] = {0.f, 0.f};

  const bf16* kptr = kbb + ((size_t)(w * 16 + l16)) * 32 + quad * 8;
  const bf16* vptr = vbb + ((size_t)(w * 32 + l16)) * 4096 + quad * 8;

  int c16w = w * 2 + (quad >> 1);
  int off8 = (quad & 1) * 4;

  auto load_kv = [&](int j0, bf16x8& kf, bf16x8 vf[2][4]) {
    kf = *(const bf16x8*)(kptr + (size_t)j0 * 32);
#pragma unroll
    for (int ci = 0; ci < 2; ci++)
#pragma unroll
      for (int kc = 0; kc < 4; kc++)
        vf[ci][kc] = *(const bf16x8*)(vptr + (size_t)ci * 16 * 4096 + j0 + kc * 32);
  };

  auto s_phase = [&](const bf16x8& kf, int pb) {
    bf16* P = Pl[pb];
#pragma unroll
    for (int nj = 0; nj < 2; nj++) {
      f32x4 s = __builtin_amdgcn_mfma_f32_16x16x32_bf16(
          kf, qf[nj], (f32x4){0.f, 0.f, 0.f, 0.f}, 0, 0, 0);
      float p0f = __expf(fminf(s[0], 80.f));
      float p1f = __expf(fminf(s[1], 80.f));
      float p2f = __expf(fminf(s[2], 80.f));
      float p3f = __expf(fminf(s[3], 80.f));
      lpart[nj] += (p0f + p1f) + (p2f + p3f);
      int row = nj * 16 + l16;
      int c16 = c16w ^ (row & 15);
      uint2 u = {pk2(p0f, p1f), pk2(p2f, p3f)};
      *(uint2*)&P[row * 128 + c16 * 8 + off8] = u;
    }
  };

  auto pv_phase = [&](const bf16x8 vf[2][4], int pb) {
    const bf16* P = Pl[pb];
#pragma unroll
    for (int kc = 0; kc < 4; kc++) {
      bf16x8 pf[2];
#pragma unroll
      for (int nj = 0; nj < 2; nj++) {
        int row = nj * 16 + l16;
        int c16 = (kc * 4 + quad) ^ (row & 15);
        pf[nj] = *(const bf16x8*)&P[row * 128 + c16 * 8];
      }
#pragma unroll
      for (int ci = 0; ci < 2; ci++)
#pragma unroll
        for (int nj = 0; nj < 2; nj++)
          acc[ci][nj] = __builtin_amdgcn_mfma_f32_16x16x32_bf16(
              vf[ci][kc], pf[nj], acc[ci][nj], 0, 0, 0);
    }
  };

  bf16x8 kfA, kfB, vfA[2][4], vfB[2][4];
  load_kv(0, kfA, vfA);
  s_phase(kfA, 0);

  for (int i = 0; i < 32; i += 2) {
    __syncthreads();
    if (i < 31) load_kv((i + 1) * 128, kfB, vfB);
    pv_phase(vfA, 0);
    if (i < 31) s_phase(kfB, 1);
    __syncthreads();
    if (i + 2 < 32) load_kv((i + 2) * 128, kfA, vfA);
    if (i + 1 < 32) pv_phase(vfB, 1);
    if (i + 2 < 32) s_phase(kfA, 0);
  }

#pragma unroll
  for (int nj = 0; nj < 2; nj++) {
    float v = lpart[nj];
    v += __shfl_xor(v, 16);
    v += __shfl_xor(v, 32);
    lpart[nj] = v;
  }
  if (lane < 16) {
#pragma unroll
    for (int nj = 0; nj < 2; nj++) lsumw[w][nj * 16 + lane] = lpart[nj];
  }
  __syncthreads();

  float gm = gamma[0];
#pragma unroll
  for (int nj = 0; nj < 2; nj++) {
    int ql = nj * 16 + l16;
    float ls = 0.f;
#pragma unroll
    for (int w8 = 0; w8 < 8; w8++) ls += lsumw[w8][ql];
    float gl = gm / ls;
#pragma unroll
    for (int ci = 0; ci < 2; ci++) {
      int cb = w * 32 + ci * 16 + quad * 4;
#pragma unroll
      for (int r = 0; r < 4; r++) {
        size_t gidx = (((size_t)(b * 256 + cb + r)) << 12) + q0 + ql;
        out[gidx] = gl * acc[ci][nj][r] + x1[gidx];
      }
    }
  }
}

// ------------------------------------------------------------------- launcher
extern "C" void kernel_launch(void* const* d_in, const int* in_sizes, int n_in,
                              void* d_out, int out_size, void* d_ws, size_t ws_size,
                              hipStream_t stream) {
  const float* x1    = (const float*)d_in[0];
  const float* x2    = (const float*)d_in[1];
  const float* w1_dw = (const float*)d_in[2];
  const float* b1_dw = (const float*)d_in[3];
  const float* w1_pw = (const float*)d_in[4];
  const float* b1_pw = (const float*)d_in[5];
  const float* bn1_g = (const float*)d_in[6];
  const float* bn1_b = (const float*)d_in[7];
  const float* bn1_m = (const float*)d_in[8];
  const float* bn1_v = (const float*)d_in[9];
  const float* w2_dw = (const float*)d_in[10];
  const float* b2_dw = (const float*)d_in[11];
  const float* w2_pw = (const float*)d_in[12];
  const float* b2_pw = (const float*)d_in[13];
  const float* bn2_g = (const float*)d_in[14];
  const float* bn2_b = (const float*)d_in[15];
  const float* bn2_m = (const float*)d_in[16];
  const float* bn2_v = (const float*)d_in[17];
  const float* wq    = (const float*)d_in[18];
  const float* bq    = (const float*)d_in[19];
  const float* wk    = (const float*)d_in[20];
  const float* bk    = (const float*)d_in[21];
  const float* wv    = (const float*)d_in[22];
  const float* bv    = (const float*)d_in[23];
  const float* gamma = (const float*)d_in[24];

  // ws layout (bf16 units): h 8.4M | x3 4.2M | x4 4.2M | qb .5M | kb .5M | v 4.2M
  bf16* wsb = (bf16*)d_ws;
  bf16* h   = wsb;
  bf16* x3  = wsb + 8388608;
  bf16* x4  = wsb + 12582912;
  bf16* qbf = wsb + 16777216;
  bf16* kbf = wsb + 17301504;
  bf16* vvb = wsb + 17825792;

  // block 1: concat(x1-x2, x1) -> dw -> pw+bn+relu -> x3
  k_dwconv2<<<dim3(256, 4), 256, 0, stream>>>(x1, x2, x1, w1_dw, b1_dw, h);
  k_gemm_mfma<<<dim3(64, 2, 4), 256, 0, stream>>>(h, w1_pw, b1_pw, bn1_g, bn1_b,
                                                  bn1_m, bn1_v, 1, 1, x3, 512);
  // block 2: concat(x1-x2, x2) -> dw -> pw+bn+relu -> x4
  k_dwconv2<<<dim3(256, 4), 256, 0, stream>>>(x1, x2, x2, w2_dw, b2_dw, h);
  k_gemm_mfma<<<dim3(64, 2, 4), 256, 0, stream>>>(h, w2_pw, b2_pw, bn2_g, bn2_b,
                                                  bn2_m, bn2_v, 1, 1, x4, 512);

  // q from x4, k from x3 ([p][32] bf16), v from x3 ([c][p] bf16)
  k_gemm_qk<<<dim3(32, 2, 4), 256, 0, stream>>>(x4, x3, wq, wk, bq, bk, qbf, kbf);
  k_gemm_mfma<<<dim3(64, 2, 4), 256, 0, stream>>>(x3, wv, bv, nullptr, nullptr,
                                                  nullptr, nullptr, 0, 0, vvb, 256);

  k_attn_mfma<<<dim3(128, 4), 512, 0, stream>>>(qbf, kbf, vvb, x1, gamma, (float*)d_out);
}